// Round 14
// baseline (1379.788 us; speedup 1.0000x reference)
//
#include <hip/hip_runtime.h>
#include <cstdint>
#include <cstddef>

// Problem constants
#define NLl 6
#define SCALEf 0.125f
#define EPSf 1e-5f
#define Hh 8

typedef __attribute__((ext_vector_type(8))) short short8;
typedef __attribute__((ext_vector_type(4))) float float4_;
typedef __attribute__((ext_vector_type(16))) float f32x16;
typedef __attribute__((ext_vector_type(4))) int int4_;
typedef __attribute__((ext_vector_type(2))) int int2_;

__device__ inline float b2f(ushort u){ union{uint i; float f;} v; v.i = ((uint)u)<<16; return v.f; }
__device__ inline ushort f2b(float f){ union{float f; uint i;} v; v.f=f; uint r = v.i + 0x7fffu + ((v.i>>16)&1u); return (ushort)(r>>16); }
__device__ inline void unpack2(uint w, float& lo, float& hi){
  union{uint i; float f;} a,b; a.i = w<<16; b.i = w & 0xffff0000u; lo=a.f; hi=b.f;
}
__device__ inline float wred(float v){
  #pragma unroll
  for(int m=32;m>=1;m>>=1) v += __shfl_xor(v, m, 64);
  return v;
}
__device__ inline f32x16 zero16(){
  f32x16 z;
  #pragma unroll
  for(int r=0;r<16;r++) z[r]=0.f;
  return z;
}
// m204 bijective XCD swizzle
__device__ inline int xcd_swz(int orig, int nwg){
  int q = nwg >> 3, r = nwg & 7;
  int x = orig & 7, idx = orig >> 3;
  return (x < r ? x*(q+1) : r*(q+1) + (x-r)*q) + idx;
}

// ---------------- fused fp32 -> bf16 conversion (16 elems/thread) + traj mean ----------------
struct CvtTab {
  const float* s[10];
  ushort* d[10];
  unsigned st[11];   // cumulative starts in 16-elem units
};
__global__ __launch_bounds__(256) void cvt_tm(CvtTab tab, unsigned nbcvt,
                                              const float* __restrict__ traj, ushort* __restrict__ tm){
  if (blockIdx.x >= nbcvt){
    int idx = (blockIdx.x - nbcvt)*256 + threadIdx.x;  // 0..65535
    float s = 0.f;
    #pragma unroll
    for(int g=0; g<8; g++) s += traj[g*65536 + idx];
    tm[idx] = f2b(s*0.125f);
    return;
  }
  unsigned g = blockIdx.x*256 + threadIdx.x;
  if (g >= tab.st[10]) return;
  int i = 0;
  #pragma unroll
  for (int k=0;k<9;k++) if (g >= tab.st[k+1]) i = k+1;
  unsigned off = g - tab.st[i];
  const float* sp = tab.s[i] + (size_t)off*16;
  ushort* dp = tab.d[i] + (size_t)off*16;
  ushort o[16];
  #pragma unroll
  for (int q=0;q<4;q++){
    float4_ v = *(const float4_*)(sp + q*4);
    o[q*4+0]=f2b(v[0]); o[q*4+1]=f2b(v[1]); o[q*4+2]=f2b(v[2]); o[q*4+3]=f2b(v[3]);
  }
  *(int4_*)(dp)   = *(const int4_*)&o[0];
  *(int4_*)(dp+8) = *(const int4_*)&o[8];
}

// ================ 256x128-tile GEMM (4 waves, wave tile 128x64, 16x16x32 MFMA) ================
// A: two r6-verified 128-row folded-XOR structures (A0 rows 0..127, A1 rows 128..255),
// 3-stage counted-vmcnt pipeline, 6 glds/wave/step (4 A + 2 B). vmcnt(6) in-loop.
// Reads stay 2-way bank-aliased (free): fa slot = ((m>>2)*4 + l4) ^ (l15&7).
template<int RELU>
__global__ __launch_bounds__(256, 2) void gemm_bias(
    const ushort* __restrict__ A, const ushort* __restrict__ W,
    const float* __restrict__ bias, ushort* __restrict__ C,
    int Ndim, int K, int nbx)
{
  __shared__ ushort As[24576];   // 3 x (A0 4096 + A1 4096)
  __shared__ ushort Bs[12288];   // 3 x 4096
  const int wg = xcd_swz(blockIdx.x, gridDim.x);
  const int bn = wg % nbx, bm = wg / nbx;
  const int rowA0 = bm*256, colB0 = bn*128;
  const int tid = threadIdx.x;
  const int wid = tid>>6, lane = tid&63;
  const int wr = wid>>1, wc = wid&1;
  const int l15 = lane & 15, l4 = lane >> 4;

  // A staging: 1024 granules/buffer; q = wid*256 + s*64 + lane
  const ushort* gA[4]; int offA[4];
  #pragma unroll
  for (int s=0;s<4;s++){
    int q = wid*256 + s*64 + lane;
    int half = q>>9, p = q&511;
    int lrow = p>>3, x = p&7;
    int logical = x ^ (lrow&7);
    int row = half*128 + (logical>>2)*64 + lrow;
    int ls = logical&3;
    gA[s] = A + (size_t)(rowA0+row)*K + ls*8;
    offA[s] = (wid*256 + s*64)*8;
  }
  // B staging: 512 granules/buffer; q = wid*128 + s*64 + lane (r12-exact)
  const ushort* gB[2]; int offB[2];
  #pragma unroll
  for (int s=0;s<2;s++){
    int p = wid*128 + s*64 + lane;
    int lrow = p>>3, x = p&7;
    int logical = x ^ (lrow&7);
    int row = (logical>>2)*64 + lrow;
    int ls = logical&3;
    gB[s] = W + (size_t)(colB0+row)*K + ls*8;
    offB[s] = (wid*128 + s*64)*8;
  }

  float4_ acc[8][4];
  #pragma unroll
  for(int i=0;i<8;i++)
    #pragma unroll
    for(int j=0;j<4;j++){ acc[i][j][0]=0.f; acc[i][j][1]=0.f; acc[i][j][2]=0.f; acc[i][j][3]=0.f; }

  const int NT = K >> 5;
  // prologue: P(0)->buf0, P(1)->buf1 (6 glds each per wave)
  #pragma unroll
  for (int s=0;s<4;s++){
    __builtin_amdgcn_global_load_lds((const unsigned int*)gA[s], (unsigned int*)(As + offA[s]), 16, 0, 0);
    gA[s] += 32;
  }
  #pragma unroll
  for (int s=0;s<2;s++){
    __builtin_amdgcn_global_load_lds((const unsigned int*)gB[s], (unsigned int*)(Bs + offB[s]), 16, 0, 0);
    gB[s] += 32;
  }
  #pragma unroll
  for (int s=0;s<4;s++){
    __builtin_amdgcn_global_load_lds((const unsigned int*)gA[s], (unsigned int*)(As + 8192 + offA[s]), 16, 0, 0);
    gA[s] += 32;
  }
  #pragma unroll
  for (int s=0;s<2;s++){
    __builtin_amdgcn_global_load_lds((const unsigned int*)gB[s], (unsigned int*)(Bs + 4096 + offB[s]), 16, 0, 0);
    gB[s] += 32;
  }

  int cur = 0;
  for (int t=0; t<NT; ++t){
    if (t+1 < NT) asm volatile("s_waitcnt vmcnt(6)" ::: "memory");
    else          asm volatile("s_waitcnt vmcnt(0)" ::: "memory");
    __builtin_amdgcn_s_barrier();
    if (t+2 < NT){
      int nb = cur+2; if (nb>=3) nb-=3;
      #pragma unroll
      for (int s=0;s<4;s++){
        __builtin_amdgcn_global_load_lds((const unsigned int*)gA[s], (unsigned int*)(As + nb*8192 + offA[s]), 16, 0, 0);
        gA[s] += 32;
      }
      #pragma unroll
      for (int s=0;s<2;s++){
        __builtin_amdgcn_global_load_lds((const unsigned int*)gB[s], (unsigned int*)(Bs + nb*4096 + offB[s]), 16, 0, 0);
        gB[s] += 32;
      }
    }
    const ushort* Apt = As + cur*8192 + wr*4096;
    const ushort* Bpt = Bs + cur*4096;
    short8 fa[8], fb[4];
    #pragma unroll
    for(int m=0;m<8;m++){
      int lrow = (m&3)*16 + l15;
      fa[m] = *(const short8*)&Apt[lrow*64 + ((((m>>2)*4 + l4) ^ (l15&7))*8)];
    }
    #pragma unroll
    for(int n=0;n<4;n++){
      int lrow = n*16 + l15;
      fb[n] = *(const short8*)&Bpt[lrow*64 + (((wc*4 + l4) ^ (l15&7))*8)];
    }
    __builtin_amdgcn_s_setprio(1);
    #pragma unroll
    for(int m=0;m<8;m++)
      #pragma unroll
      for(int n=0;n<4;n++)
        acc[m][n] = __builtin_amdgcn_mfma_f32_16x16x32_bf16(fa[m], fb[n], acc[m][n], 0,0,0);
    __builtin_amdgcn_s_setprio(0);
    cur = (cur==2) ? 0 : cur+1;
  }

  // epilogue: rows wr*128 + (m>>2)*64 + (m&3)*16 + l4*4 + r  (fa[m] covers A-half m>>2)
  #pragma unroll
  for(int m=0;m<8;m++){
    int grow = rowA0 + wr*128 + (m>>2)*64 + (m&3)*16 + l4*4;
    #pragma unroll
    for(int n=0;n<4;n++){
      int gcol = colB0 + wc*64 + n*16 + l15;
      float bv = bias[gcol];
      #pragma unroll
      for(int r=0;r<4;r++){
        float v = acc[m][n][r] + bv;
        if (RELU) v = fmaxf(v, 0.f);
        C[(size_t)(grow + r)*Ndim + gcol] = f2b(v);
      }
    }
  }
}

// ---------------- 128x128 GEMM core (r12-exact, for the 128-row kv_all) ----------------
__device__ __forceinline__ void gemm_core128(
    const ushort* __restrict__ A, const ushort* __restrict__ W,
    const float* __restrict__ bias, ushort* __restrict__ C,
    int Ndim, int K, int rowA0, int colB0,
    ushort* As, ushort* Bs)
{
  const int tid = threadIdx.x;
  const int wid = tid>>6, lane = tid&63;
  const int wr = wid>>1, wc = wid&1;
  const int l15 = lane & 15, l4 = lane >> 4;

  const ushort* gA[2]; const ushort* gB[2];
  int ldsOff[2];
  #pragma unroll
  for (int s=0;s<2;s++){
    int p = wid*128 + s*64 + lane;
    int lrow = p>>3, x = p&7;
    int logical = x ^ (lrow&7);
    int row = (logical>>2)*64 + lrow;
    int ls = logical&3;
    gA[s] = A + (size_t)(rowA0+row)*K + ls*8;
    gB[s] = W + (size_t)(colB0+row)*K + ls*8;
    ldsOff[s] = wid*1024 + s*512;
  }

  float4_ acc[4][4];
  #pragma unroll
  for(int i=0;i<4;i++)
    #pragma unroll
    for(int j=0;j<4;j++){ acc[i][j][0]=0.f; acc[i][j][1]=0.f; acc[i][j][2]=0.f; acc[i][j][3]=0.f; }

  const int NT = K >> 5;
  #pragma unroll
  for (int s=0;s<2;s++){
    __builtin_amdgcn_global_load_lds((const unsigned int*)gA[s], (unsigned int*)(As + ldsOff[s]), 16, 0, 0);
    __builtin_amdgcn_global_load_lds((const unsigned int*)gB[s], (unsigned int*)(Bs + ldsOff[s]), 16, 0, 0);
    gA[s] += 32; gB[s] += 32;
  }
  if (NT > 1){
    #pragma unroll
    for (int s=0;s<2;s++){
      __builtin_amdgcn_global_load_lds((const unsigned int*)gA[s], (unsigned int*)(As + 4096 + ldsOff[s]), 16, 0, 0);
      __builtin_amdgcn_global_load_lds((const unsigned int*)gB[s], (unsigned int*)(Bs + 4096 + ldsOff[s]), 16, 0, 0);
      gA[s] += 32; gB[s] += 32;
    }
  }

  int cur = 0;
  for (int t=0; t<NT; ++t){
    if (t+1 < NT) asm volatile("s_waitcnt vmcnt(4)" ::: "memory");
    else          asm volatile("s_waitcnt vmcnt(0)" ::: "memory");
    __builtin_amdgcn_s_barrier();
    if (t+2 < NT){
      int nb = cur+2; if (nb>=3) nb-=3;
      #pragma unroll
      for (int s=0;s<2;s++){
        __builtin_amdgcn_global_load_lds((const unsigned int*)gA[s], (unsigned int*)(As + nb*4096 + ldsOff[s]), 16, 0, 0);
        __builtin_amdgcn_global_load_lds((const unsigned int*)gB[s], (unsigned int*)(Bs + nb*4096 + ldsOff[s]), 16, 0, 0);
        gA[s] += 32; gB[s] += 32;
      }
    }
    const ushort* Apt = As + cur*4096;
    const ushort* Bpt = Bs + cur*4096;
    short8 fa[4], fb[4];
    #pragma unroll
    for(int m=0;m<4;m++){
      int lrow = m*16 + l15;
      fa[m] = *(const short8*)&Apt[lrow*64 + (((wr*4 + l4) ^ (l15&7))*8)];
    }
    #pragma unroll
    for(int n=0;n<4;n++){
      int lrow = n*16 + l15;
      fb[n] = *(const short8*)&Bpt[lrow*64 + (((wc*4 + l4) ^ (l15&7))*8)];
    }
    __builtin_amdgcn_s_setprio(1);
    #pragma unroll
    for(int m=0;m<4;m++)
      #pragma unroll
      for(int n=0;n<4;n++)
        acc[m][n] = __builtin_amdgcn_mfma_f32_16x16x32_bf16(fa[m], fb[n], acc[m][n], 0,0,0);
    __builtin_amdgcn_s_setprio(0);
    cur = (cur==2) ? 0 : cur+1;
  }

  #pragma unroll
  for(int m=0;m<4;m++){
    int grow = rowA0 + wr*64 + m*16 + l4*4;
    #pragma unroll
    for(int n=0;n<4;n++){
      int gcol = colB0 + wc*64 + n*16 + l15;
      float bv = bias[gcol];
      #pragma unroll
      for(int r=0;r<4;r++){
        float v = acc[m][n][r] + bv;
        C[(size_t)(grow + r)*Ndim + gcol] = f2b(v);
      }
    }
  }
}

// all 6 layers' cross-attn K,V projections of the 128-row traj mean
__global__ __launch_bounds__(256, 3) void kv_all(
    const ushort* __restrict__ tm,
    const ushort* __restrict__ wk, const ushort* __restrict__ wv,
    const float* __restrict__ bk, const float* __restrict__ bv,
    ushort* __restrict__ KVm)
{
  __shared__ ushort As[12288];
  __shared__ ushort Bs[12288];
  const int i = blockIdx.x >> 3;
  const int r8 = blockIdx.x & 7;
  const int which = r8 >> 2, bn = r8 & 3;
  const ushort* W  = (which ? wv : wk) + (size_t)i*262144;
  const float* bias = (which ? bv : bk) + i*512;
  ushort* C = KVm + (size_t)(i*2 + which)*65536;
  gemm_core128(tm, W, bias, C, 512, 512, 0, bn*128, As, Bs);
}

// ---------------- MFMA flash attention (swapped QK^T, 32x32x16) ----------------
template<int NKEYS, int WRITE_ATTN, int KPF>
__global__ __launch_bounds__(256) void attn_mfma(
  const ushort* __restrict__ Qb, int qstr,
  const ushort* __restrict__ Kb, int kstr,
  const ushort* __restrict__ Vb, int vstr,
  ushort* __restrict__ Ob,
  float* __restrict__ attn_out)
{
  constexpr int NK2 = NKEYS*2;
  __shared__ __align__(16) ushort KsV[NKEYS*64 + 64*NKEYS];
  const int f = blockIdx.x, h = blockIdx.y;
  const int tid = threadIdx.x, lane = tid & 63, w = tid >> 6;
  const int l31 = lane & 31, l5 = lane >> 5;
  const int swz = (lane & 7) << 4;

  ushort* Ks = KsV;
  ushort* Vt = KsV + NKEYS*64;
  float* psum = (float*)Vt;   // aliased; pass 2 only, after barrier
  const ushort* kp0 = Kb + (size_t)(KPF ? f*256 : 0)*kstr + h*64;
  const ushort* vp0 = Vb + (size_t)(KPF ? f*256 : 0)*vstr + h*64;

  for (int c = tid; c < NKEYS*8; c += 256){
    int m = c>>3, dc = c&7;
    short8 k8 = *(const short8*)(kp0 + (size_t)m*kstr + dc*8);
    short8 v8 = *(const short8*)(vp0 + (size_t)m*vstr + dc*8);
    *(short8*)((char*)Ks + m*128 + ((dc*16) ^ ((m&7)<<4))) = k8;
    #pragma unroll
    for (int j=0;j<8;j++){
      int d = dc*8 + j;
      *(ushort*)((char*)Vt + d*NK2 + ((m*2) ^ (j<<4))) = (ushort)v8[j];
    }
  }

  short8 qb[2][4];
  const int q0 = w*64;
  const ushort* qp0 = Qb + (size_t)(f*256)*qstr + h*64;
  #pragma unroll
  for (int qj=0;qj<2;qj++)
    #pragma unroll
    for (int dc=0;dc<4;dc++)
      qb[qj][dc] = *(const short8*)(qp0 + (size_t)(q0 + qj*32 + l31)*qstr + dc*16 + l5*8);
  __syncthreads();

  f32x16 O[2][2];
  O[0][0]=zero16(); O[0][1]=zero16(); O[1][0]=zero16(); O[1][1]=zero16();
  float lpart[2] = {0.f, 0.f};

  for (int t = 0; t < NKEYS/32; t++){
    const int k0 = t*32;
    short8 ka[4];
    #pragma unroll
    for (int dc=0;dc<4;dc++)
      ka[dc] = *(const short8*)((char*)Ks + (k0+l31)*128 + (((dc*32) + (l5*16)) ^ swz));
    f32x16 s0 = zero16(), s1 = zero16();
    #pragma unroll
    for (int dc=0;dc<4;dc++){
      s0 = __builtin_amdgcn_mfma_f32_32x32x16_bf16(ka[dc], qb[0][dc], s0, 0,0,0);
      s1 = __builtin_amdgcn_mfma_f32_32x32x16_bf16(ka[dc], qb[1][dc], s1, 0,0,0);
    }
    uint pw[2][8];
    #pragma unroll
    for (int qj=0;qj<2;qj++){
      const f32x16& sv = qj ? s1 : s0;
      float p[16]; float lp = 0.f;
      #pragma unroll
      for (int r=0;r<16;r++){ p[r] = __expf(sv[r]*SCALEf); lp += p[r]; }
      lpart[qj] += lp;
      #pragma unroll
      for (int k=0;k<8;k++){
        uint w_;
        asm("v_cvt_pk_bf16_f32 %0, %1, %2" : "=v"(w_) : "v"(p[2*k]), "v"(p[2*k+1]));
        pw[qj][k] = w_;
      }
    }
    short8 pa[2][2];
    #pragma unroll
    for (int qj=0;qj<2;qj++){
      #pragma unroll
      for (int mj=0;mj<2;mj++){
        uint a0 = pw[qj][mj*4+2], b0 = pw[qj][mj*4+0];
        uint a1 = pw[qj][mj*4+3], b1 = pw[qj][mj*4+1];
        asm("v_permlane32_swap_b32 %0, %1" : "+v"(a0), "+v"(b0));
        asm("v_permlane32_swap_b32 %0, %1" : "+v"(a1), "+v"(b1));
        union { uint u[4]; short8 s8; } u_;
        u_.u[0]=b0; u_.u[1]=b1; u_.u[2]=a0; u_.u[3]=a1;
        pa[qj][mj] = u_.s8;
      }
    }
    #pragma unroll
    for (int mj=0;mj<2;mj++){
      short8 vbf[2];
      #pragma unroll
      for (int dj=0;dj<2;dj++)
        vbf[dj] = *(const short8*)((char*)Vt + (dj*32+l31)*NK2 + (((k0 + mj*16 + l5*8)*2) ^ swz));
      #pragma unroll
      for (int qj=0;qj<2;qj++)
        #pragma unroll
        for (int dj=0;dj<2;dj++)
          O[qj][dj] = __builtin_amdgcn_mfma_f32_32x32x16_bf16(pa[qj][mj], vbf[dj], O[qj][dj], 0,0,0);
    }
  }

  float invl[2];
  #pragma unroll
  for (int qj=0;qj<2;qj++){
    float lt = lpart[qj] + __shfl_xor(lpart[qj], 32, 64);
    invl[qj] = 1.f / lt;
  }

  ushort* op0 = Ob + (size_t)(f*256)*512 + h*64;
  #pragma unroll
  for (int qj=0;qj<2;qj++){
    #pragma unroll
    for (int r=0;r<16;r++){
      int qr = (r&3) + 8*(r>>2) + 4*l5;
      float il = __shfl(invl[qj], (lane & 32) | qr, 64);
      #pragma unroll
      for (int dj=0;dj<2;dj++){
        float v = O[qj][dj][r] * il;
        op0[(size_t)(q0 + qj*32 + qr)*512 + dj*32 + l31] = f2b(v);
      }
    }
  }

  if (WRITE_ATTN){
    __syncthreads();   // all waves done with Vt before psum aliases it
    for (int t = 0; t < NKEYS/32; t++){
      const int k0 = t*32;
      short8 ka[4];
      #pragma unroll
      for (int dc=0;dc<4;dc++)
        ka[dc] = *(const short8*)((char*)Ks + (k0+l31)*128 + (((dc*32) + (l5*16)) ^ swz));
      f32x16 s0 = zero16(), s1 = zero16();
      #pragma unroll
      for (int dc=0;dc<4;dc++){
        s0 = __builtin_amdgcn_mfma_f32_32x32x16_bf16(ka[dc], qb[0][dc], s0, 0,0,0);
        s1 = __builtin_amdgcn_mfma_f32_32x32x16_bf16(ka[dc], qb[1][dc], s1, 0,0,0);
      }
      float tsum[16];
      #pragma unroll
      for (int r=0;r<16;r++){
        float v = __expf(s0[r]*SCALEf)*invl[0] + __expf(s1[r]*SCALEf)*invl[1];
        #pragma unroll
        for (int mk=1; mk<=16; mk<<=1) v += __shfl_xor(v, mk, 64);
        tsum[r] = v;
      }
      if (l31 == 0){
        #pragma unroll
        for (int r=0;r<16;r++)
          psum[w*NKEYS + k0 + (r&3) + 8*(r>>2) + 4*l5] = tsum[r];
      }
    }
    __syncthreads();
    for (int m = tid; m < NKEYS; m += 256){
      attn_out[f*(Hh*NKEYS) + h*NKEYS + m] =
        (psum[0*NKEYS+m]+psum[1*NKEYS+m]+psum[2*NKEYS+m]+psum[3*NKEYS+m]) * (1.0f/256.0f);
    }
  }
}

// ---------------- Residual + LayerNorm (D=512), wave per row ----------------
__global__ __launch_bounds__(256) void ln_res(
  const ushort* __restrict__ X, const ushort* __restrict__ Oin,
  const float* __restrict__ g, const float* __restrict__ b,
  ushort* __restrict__ Y)
{
  const int row = blockIdx.x*4 + (threadIdx.x>>6);
  const int lane = threadIdx.x & 63;
  const ushort* xp = X + (size_t)row*512 + lane*8;
  const ushort* op = Oin + (size_t)row*512 + lane*8;
  uint xw[4], ow[4];
  *(int4_*)xw = *(const int4_*)xp;
  *(int4_*)ow = *(const int4_*)op;
  float v[8];
  #pragma unroll
  for(int j=0;j<4;j++){
    float xl,xh,ol,oh; unpack2(xw[j],xl,xh); unpack2(ow[j],ol,oh);
    v[2*j] = xl+ol; v[2*j+1] = xh+oh;
  }
  float s=0.f, sq=0.f;
  #pragma unroll
  for(int j=0;j<8;j++){ s += v[j]; sq += v[j]*v[j]; }
  s = wred(s); sq = wred(sq);
  float mu = s * (1.0f/512.0f);
  float var = sq * (1.0f/512.0f) - mu*mu;
  float rs = rsqrtf(var + EPSf);
  ushort ob[8];
  #pragma unroll
  for(int j=0;j<8;j++){
    ob[j] = f2b((v[j]-mu)*rs*g[lane*8+j] + b[lane*8+j]);
  }
  *(int4_*)(Y + (size_t)row*512 + lane*8) = *(const int4_*)ob;
}

// ---------------- Final LN (FD=256) -> fp32 d_out ----------------
__global__ __launch_bounds__(256) void ln_out(
  const ushort* __restrict__ A, const float* __restrict__ g,
  const float* __restrict__ b, float* __restrict__ out)
{
  const int row = blockIdx.x*4 + (threadIdx.x>>6);
  const int lane = threadIdx.x & 63;
  uint aw[2];
  *(int2_*)aw = *(const int2_*)(A + (size_t)row*256 + lane*4);
  float v[4];
  unpack2(aw[0], v[0], v[1]); unpack2(aw[1], v[2], v[3]);
  float s=0.f, sq=0.f;
  #pragma unroll
  for(int j=0;j<4;j++){ s += v[j]; sq += v[j]*v[j]; }
  s = wred(s); sq = wred(sq);
  float mu = s * (1.0f/256.0f);
  float var = sq * (1.0f/256.0f) - mu*mu;
  float rs = rsqrtf(var + EPSf);
  float4_ o;
  #pragma unroll
  for(int j=0;j<4;j++){
    o[j] = (v[j]-mu)*rs*g[lane*4+j] + b[lane*4+j];
  }
  *(float4_*)(out + (size_t)row*256 + lane*4) = o;
}

extern "C" void kernel_launch(void* const* d_in, const int* in_sizes, int n_in,
                              void* d_out, int out_size, void* d_ws, size_t ws_size,
                              hipStream_t stream) {
  const float* cur      = (const float*)d_in[0];
  const float* traj     = (const float*)d_in[1];
  const float* sa_in_w  = (const float*)d_in[2];
  const float* sa_in_b  = (const float*)d_in[3];
  const float* sa_out_w = (const float*)d_in[4];
  const float* sa_out_b = (const float*)d_in[5];
  const float* n1_g     = (const float*)d_in[6];
  const float* n1_b     = (const float*)d_in[7];
  const float* ca_qw    = (const float*)d_in[8];
  const float* ca_qb    = (const float*)d_in[9];
  const float* ca_kw    = (const float*)d_in[10];
  const float* ca_kb    = (const float*)d_in[11];
  const float* ca_vw    = (const float*)d_in[12];
  const float* ca_vb    = (const float*)d_in[13];
  const float* ca_ow    = (const float*)d_in[14];
  const float* ca_ob    = (const float*)d_in[15];
  const float* n2_g     = (const float*)d_in[16];
  const float* n2_b     = (const float*)d_in[17];
  const float* f_w1     = (const float*)d_in[18];
  const float* f_b1     = (const float*)d_in[19];
  const float* f_w2     = (const float*)d_in[20];
  const float* f_b2     = (const float*)d_in[21];
  const float* n3_g     = (const float*)d_in[22];
  const float* n3_b     = (const float*)d_in[23];
  const float* out_w    = (const float*)d_in[24];
  const float* out_b    = (const float*)d_in[25];
  const float* on_g     = (const float*)d_in[26];
  const float* on_b     = (const float*)d_in[27];

  float* out      = (float*)d_out;
  float* attn_out = out + (size_t)4*16*256*256;

  uint8_t* ws = (uint8_t*)d_ws;
  size_t off = 0;
  auto alloc = [&](size_t bytes)->uint8_t*{ uint8_t* p = ws + off; off += (bytes + 255) & ~(size_t)255; return p; };
  ushort* X   = (ushort*)alloc(16777216);
  ushort* B1  = (ushort*)alloc(50331648);
  ushort* B2  = (ushort*)alloc(16777216);
  ushort* KVm = (ushort*)alloc((size_t)6*2*65536*2);
  ushort* tm  = (ushort*)alloc(131072);
  ushort* w_sa_in  = (ushort*)alloc((size_t)5*1536*512*2);
  ushort* w_sa_out = (ushort*)alloc((size_t)5*512*512*2);
  ushort* w_ca_q   = (ushort*)alloc((size_t)6*512*512*2);
  ushort* w_ca_k   = (ushort*)alloc((size_t)6*512*512*2);
  ushort* w_ca_v   = (ushort*)alloc((size_t)6*512*512*2);
  ushort* w_ca_o   = (ushort*)alloc((size_t)6*512*512*2);
  ushort* w_f1     = (ushort*)alloc((size_t)6*1024*512*2);
  ushort* w_f2     = (ushort*)alloc((size_t)6*512*1024*2);
  ushort* w_out    = (ushort*)alloc((size_t)256*512*2);

  // one fused conversion + tmean dispatch
  CvtTab tab;
  const float* srcs[10] = {cur, sa_in_w, sa_out_w, ca_qw, ca_kw, ca_vw, ca_ow, f_w1, f_w2, out_w};
  ushort* dsts[10]      = {X,   w_sa_in, w_sa_out, w_ca_q, w_ca_k, w_ca_v, w_ca_o, w_f1, w_f2, w_out};
  unsigned lens[10] = {16384u*512u, 5u*1536u*512u, 5u*512u*512u, 6u*512u*512u, 6u*512u*512u,
                       6u*512u*512u, 6u*512u*512u, 6u*1024u*512u, 6u*512u*1024u, 256u*512u};
  unsigned acc16 = 0;
  for (int i=0;i<10;i++){ tab.s[i]=srcs[i]; tab.d[i]=dsts[i]; tab.st[i]=acc16; acc16 += lens[i]/16; }
  tab.st[10] = acc16;
  unsigned nbcvt = (acc16 + 255)/256;
  cvt_tm<<<nbcvt + 256, 256, 0, stream>>>(tab, nbcvt, traj, tm);
  kv_all<<<48,256,0,stream>>>(tm, w_ca_k, w_ca_v, ca_kb, ca_vb, KVm);

  for (int i=0;i<NLl;i++){
    if (i>=1){
      int j = i-1;
      gemm_bias<0><<<64*12,256,0,stream>>>(X, w_sa_in + (size_t)j*1536*512, sa_in_b + j*1536, B1, 1536, 512, 12);
      attn_mfma<256,0,1><<<dim3(64,8),256,0,stream>>>(B1, 1536, B1+512, 1536, B1+1024, 1536, B2, nullptr);
      gemm_bias<0><<<64*4,256,0,stream>>>(B2, w_sa_out + (size_t)j*262144, sa_out_b + j*512, B1, 512, 512, 4);
      ln_res<<<4096,256,0,stream>>>(X, B1, n1_g + j*512, n1_b + j*512, X);
    }
    gemm_bias<0><<<64*4,256,0,stream>>>(X, w_ca_q + (size_t)i*262144, ca_qb + i*512, B2, 512, 512, 4);
    attn_mfma<128,1,0><<<dim3(64,8),256,0,stream>>>(B2, 512, KVm + (size_t)i*131072, 512, KVm + (size_t)i*131072 + 65536, 512, B1, attn_out + (size_t)i*65536);
    gemm_bias<0><<<64*4,256,0,stream>>>(B1, w_ca_o + (size_t)i*262144, ca_ob + i*512, B2, 512, 512, 4);
    ln_res<<<4096,256,0,stream>>>(X, B2, n2_g + i*512, n2_b + i*512, X);
    gemm_bias<1><<<64*8,256,0,stream>>>(X, w_f1 + (size_t)i*524288, f_b1 + i*1024, B1, 1024, 512, 8);
    gemm_bias<0><<<64*4,256,0,stream>>>(B1, w_f2 + (size_t)i*524288, f_b2 + i*512, B2, 512, 1024, 4);
    ln_res<<<4096,256,0,stream>>>(X, B2, n3_g + i*512, n3_b + i*512, X);
  }
  gemm_bias<0><<<64*2,256,0,stream>>>(X, w_out, out_b, B2, 256, 512, 2);
  ln_out<<<4096,256,0,stream>>>(B2, on_g, on_b, out);
}

// Round 15
// 1234.888 us; speedup vs baseline: 1.1173x; 1.1173x over previous
//
#include <hip/hip_runtime.h>
#include <cstdint>
#include <cstddef>

// Problem constants
#define NLl 6
#define SCALEf 0.125f
#define EPSf 1e-5f
#define Hh 8

typedef __attribute__((ext_vector_type(8))) short short8;
typedef __attribute__((ext_vector_type(4))) float float4_;
typedef __attribute__((ext_vector_type(16))) float f32x16;
typedef __attribute__((ext_vector_type(4))) int int4_;
typedef __attribute__((ext_vector_type(2))) int int2_;

__device__ inline float b2f(ushort u){ union{uint i; float f;} v; v.i = ((uint)u)<<16; return v.f; }
__device__ inline ushort f2b(float f){ union{float f; uint i;} v; v.f=f; uint r = v.i + 0x7fffu + ((v.i>>16)&1u); return (ushort)(r>>16); }
__device__ inline void unpack2(uint w, float& lo, float& hi){
  union{uint i; float f;} a,b; a.i = w<<16; b.i = w & 0xffff0000u; lo=a.f; hi=b.f;
}
__device__ inline float wred(float v){
  #pragma unroll
  for(int m=32;m>=1;m>>=1) v += __shfl_xor(v, m, 64);
  return v;
}
__device__ inline f32x16 zero16(){
  f32x16 z;
  #pragma unroll
  for(int r=0;r<16;r++) z[r]=0.f;
  return z;
}
// m204 bijective XCD swizzle
__device__ inline int xcd_swz(int orig, int nwg){
  int q = nwg >> 3, r = nwg & 7;
  int x = orig & 7, idx = orig >> 3;
  return (x < r ? x*(q+1) : r*(q+1) + (x-r)*q) + idx;
}

// ---------------- fused fp32 -> bf16 conversion (8 elems/thread) + traj mean ----------------
struct CvtTab {
  const float* s[10];
  ushort* d[10];
  unsigned st[11];   // cumulative starts in 8-elem units
};
__global__ __launch_bounds__(256) void cvt_tm(CvtTab tab, unsigned nbcvt,
                                              const float* __restrict__ traj, ushort* __restrict__ tm){
  if (blockIdx.x >= nbcvt){
    int idx = (blockIdx.x - nbcvt)*256 + threadIdx.x;  // 0..65535
    float s = 0.f;
    #pragma unroll
    for(int g=0; g<8; g++) s += traj[g*65536 + idx];
    tm[idx] = f2b(s*0.125f);
    return;
  }
  unsigned g = blockIdx.x*256 + threadIdx.x;
  if (g >= tab.st[10]) return;
  int i = 0;
  #pragma unroll
  for (int k=0;k<9;k++) if (g >= tab.st[k+1]) i = k+1;
  unsigned off = g - tab.st[i];
  const float* sp = tab.s[i] + (size_t)off*8;
  ushort* dp = tab.d[i] + (size_t)off*8;
  float4_ v0 = *(const float4_*)(sp);
  float4_ v1 = *(const float4_*)(sp + 4);
  ushort o[8] = {f2b(v0[0]),f2b(v0[1]),f2b(v0[2]),f2b(v0[3]),
                 f2b(v1[0]),f2b(v1[1]),f2b(v1[2]),f2b(v1[3])};
  *(int4_*)(dp) = *(const int4_*)&o[0];
}

// ================ 128x128-tile GEMM, 8 waves (2M x 4N), BK=32, 3-stage counted-vmcnt ================
// Same folded 8-slot-XOR LDS layout as r12 (0 bank conflicts, glds-linear).
// 512 threads: staging = exactly 1 granule/thread/array; per wave 1 glds per array per step.
// Ledger: prologue 4 outstanding; loop vmcnt(2) [P(t) landed, P(t+1) flying]; final vmcnt(0).
template<int RELU>
__global__ __launch_bounds__(512, 4) void gemm_bias(
    const ushort* __restrict__ A, const ushort* __restrict__ W,
    const float* __restrict__ bias, ushort* __restrict__ C,
    int Ndim, int K, int nbx)
{
  __shared__ ushort As[12288];
  __shared__ ushort Bs[12288];
  const int wg = xcd_swz(blockIdx.x, gridDim.x);
  const int bn = wg % nbx, bm = wg / nbx;
  const int rowA0 = bm*128, colB0 = bn*128;
  const int tid = threadIdx.x;
  const int wid = tid>>6, lane = tid&63;
  const int wr = wid>>2, wc = wid&3;   // 2M x 4N wave tiling (wave tile 64x32)
  const int l15 = lane & 15, l4 = lane >> 4;

  // staging map: granule q = tid; row=(logical>>2)*64 + (q>>3), logical=(q&7)^((q>>3)&7)
  const ushort* gA; const ushort* gB;
  int ldsOff;
  {
    int p = tid;
    int lrow = p>>3, x = p&7;
    int logical = x ^ (lrow&7);
    int row = (logical>>2)*64 + lrow;
    int ls = logical&3;
    gA = A + (size_t)(rowA0+row)*K + ls*8;
    gB = W + (size_t)(colB0+row)*K + ls*8;
    ldsOff = wid*512;   // wave-uniform base (elems); +lane*16B by glds
  }

  float4_ acc[2][4];
  #pragma unroll
  for(int i=0;i<2;i++)
    #pragma unroll
    for(int j=0;j<4;j++){ acc[i][j][0]=0.f; acc[i][j][1]=0.f; acc[i][j][2]=0.f; acc[i][j][3]=0.f; }

  const int NT = K >> 5;
  // prologue: P(0)->buf0, P(1)->buf1
  __builtin_amdgcn_global_load_lds((const unsigned int*)gA, (unsigned int*)(As + ldsOff), 16, 0, 0);
  __builtin_amdgcn_global_load_lds((const unsigned int*)gB, (unsigned int*)(Bs + ldsOff), 16, 0, 0);
  gA += 32; gB += 32;
  __builtin_amdgcn_global_load_lds((const unsigned int*)gA, (unsigned int*)(As + 4096 + ldsOff), 16, 0, 0);
  __builtin_amdgcn_global_load_lds((const unsigned int*)gB, (unsigned int*)(Bs + 4096 + ldsOff), 16, 0, 0);
  gA += 32; gB += 32;

  int cur = 0;
  for (int t=0; t<NT; ++t){
    if (t+1 < NT) asm volatile("s_waitcnt vmcnt(2)" ::: "memory");
    else          asm volatile("s_waitcnt vmcnt(0)" ::: "memory");
    __builtin_amdgcn_s_barrier();
    if (t+2 < NT){
      int nb = cur+2; if (nb>=3) nb-=3;
      __builtin_amdgcn_global_load_lds((const unsigned int*)gA, (unsigned int*)(As + nb*4096 + ldsOff), 16, 0, 0);
      __builtin_amdgcn_global_load_lds((const unsigned int*)gB, (unsigned int*)(Bs + nb*4096 + ldsOff), 16, 0, 0);
      gA += 32; gB += 32;
    }
    const ushort* Apt = As + cur*4096;
    const ushort* Bpt = Bs + cur*4096;
    short8 fa[4], fb[2];
    #pragma unroll
    for(int m=0;m<4;m++){
      int lrow = m*16 + l15;
      fa[m] = *(const short8*)&Apt[lrow*64 + (((wr*4 + l4) ^ (l15&7))*8)];
    }
    #pragma unroll
    for(int n=0;n<2;n++){
      int lrow = (wc&1)*32 + n*16 + l15;
      fb[n] = *(const short8*)&Bpt[lrow*64 + ((((wc>>1)*4 + l4) ^ (l15&7))*8)];
    }
    __builtin_amdgcn_s_setprio(1);
    #pragma unroll
    for(int m=0;m<4;m++)
      #pragma unroll
      for(int n=0;n<2;n++)
        acc[n][m] = __builtin_amdgcn_mfma_f32_16x16x32_bf16(fa[m], fb[n], acc[n][m], 0,0,0);
    __builtin_amdgcn_s_setprio(0);
    cur = (cur==2) ? 0 : cur+1;
  }

  #pragma unroll
  for(int m=0;m<4;m++){
    int grow0 = rowA0 + wr*64 + m*16 + l4*4;
    #pragma unroll
    for(int n=0;n<2;n++){
      int gcol = colB0 + wc*32 + n*16 + l15;
      float bv = bias[gcol];
      #pragma unroll
      for(int r=0;r<4;r++){
        float v = acc[n][m][r] + bv;
        if (RELU) v = fmaxf(v, 0.f);
        C[(size_t)(grow0 + r)*Ndim + gcol] = f2b(v);
      }
    }
  }
}

// ---------------- 128x128 GEMM core (r12-exact, 256 threads, for kv_all) ----------------
__device__ __forceinline__ void gemm_core128(
    const ushort* __restrict__ A, const ushort* __restrict__ W,
    const float* __restrict__ bias, ushort* __restrict__ C,
    int Ndim, int K, int rowA0, int colB0,
    ushort* As, ushort* Bs)
{
  const int tid = threadIdx.x;
  const int wid = tid>>6, lane = tid&63;
  const int wr = wid>>1, wc = wid&1;
  const int l15 = lane & 15, l4 = lane >> 4;

  const ushort* gA[2]; const ushort* gB[2];
  int ldsOff[2];
  #pragma unroll
  for (int s=0;s<2;s++){
    int p = wid*128 + s*64 + lane;
    int lrow = p>>3, x = p&7;
    int logical = x ^ (lrow&7);
    int row = (logical>>2)*64 + lrow;
    int ls = logical&3;
    gA[s] = A + (size_t)(rowA0+row)*K + ls*8;
    gB[s] = W + (size_t)(colB0+row)*K + ls*8;
    ldsOff[s] = wid*1024 + s*512;
  }

  float4_ acc[4][4];
  #pragma unroll
  for(int i=0;i<4;i++)
    #pragma unroll
    for(int j=0;j<4;j++){ acc[i][j][0]=0.f; acc[i][j][1]=0.f; acc[i][j][2]=0.f; acc[i][j][3]=0.f; }

  const int NT = K >> 5;
  #pragma unroll
  for (int s=0;s<2;s++){
    __builtin_amdgcn_global_load_lds((const unsigned int*)gA[s], (unsigned int*)(As + ldsOff[s]), 16, 0, 0);
    __builtin_amdgcn_global_load_lds((const unsigned int*)gB[s], (unsigned int*)(Bs + ldsOff[s]), 16, 0, 0);
    gA[s] += 32; gB[s] += 32;
  }
  if (NT > 1){
    #pragma unroll
    for (int s=0;s<2;s++){
      __builtin_amdgcn_global_load_lds((const unsigned int*)gA[s], (unsigned int*)(As + 4096 + ldsOff[s]), 16, 0, 0);
      __builtin_amdgcn_global_load_lds((const unsigned int*)gB[s], (unsigned int*)(Bs + 4096 + ldsOff[s]), 16, 0, 0);
      gA[s] += 32; gB[s] += 32;
    }
  }

  int cur = 0;
  for (int t=0; t<NT; ++t){
    if (t+1 < NT) asm volatile("s_waitcnt vmcnt(4)" ::: "memory");
    else          asm volatile("s_waitcnt vmcnt(0)" ::: "memory");
    __builtin_amdgcn_s_barrier();
    if (t+2 < NT){
      int nb = cur+2; if (nb>=3) nb-=3;
      #pragma unroll
      for (int s=0;s<2;s++){
        __builtin_amdgcn_global_load_lds((const unsigned int*)gA[s], (unsigned int*)(As + nb*4096 + ldsOff[s]), 16, 0, 0);
        __builtin_amdgcn_global_load_lds((const unsigned int*)gB[s], (unsigned int*)(Bs + nb*4096 + ldsOff[s]), 16, 0, 0);
        gA[s] += 32; gB[s] += 32;
      }
    }
    const ushort* Apt = As + cur*4096;
    const ushort* Bpt = Bs + cur*4096;
    short8 fa[4], fb[4];
    #pragma unroll
    for(int m=0;m<4;m++){
      int lrow = m*16 + l15;
      fa[m] = *(const short8*)&Apt[lrow*64 + (((wr*4 + l4) ^ (l15&7))*8)];
    }
    #pragma unroll
    for(int n=0;n<4;n++){
      int lrow = n*16 + l15;
      fb[n] = *(const short8*)&Bpt[lrow*64 + (((wc*4 + l4) ^ (l15&7))*8)];
    }
    __builtin_amdgcn_s_setprio(1);
    #pragma unroll
    for(int m=0;m<4;m++)
      #pragma unroll
      for(int n=0;n<4;n++)
        acc[m][n] = __builtin_amdgcn_mfma_f32_16x16x32_bf16(fa[m], fb[n], acc[m][n], 0,0,0);
    __builtin_amdgcn_s_setprio(0);
    cur = (cur==2) ? 0 : cur+1;
  }

  #pragma unroll
  for(int m=0;m<4;m++){
    int grow = rowA0 + wr*64 + m*16 + l4*4;
    #pragma unroll
    for(int n=0;n<4;n++){
      int gcol = colB0 + wc*64 + n*16 + l15;
      float bv = bias[gcol];
      #pragma unroll
      for(int r=0;r<4;r++){
        float v = acc[m][n][r] + bv;
        C[(size_t)(grow + r)*Ndim + gcol] = f2b(v);
      }
    }
  }
}

// all 6 layers' cross-attn K,V projections of the 128-row traj mean
__global__ __launch_bounds__(256, 3) void kv_all(
    const ushort* __restrict__ tm,
    const ushort* __restrict__ wk, const ushort* __restrict__ wv,
    const float* __restrict__ bk, const float* __restrict__ bv,
    ushort* __restrict__ KVm)
{
  __shared__ ushort As[12288];
  __shared__ ushort Bs[12288];
  const int i = blockIdx.x >> 3;
  const int r8 = blockIdx.x & 7;
  const int which = r8 >> 2, bn = r8 & 3;
  const ushort* W  = (which ? wv : wk) + (size_t)i*262144;
  const float* bias = (which ? bv : bk) + i*512;
  ushort* C = KVm + (size_t)(i*2 + which)*65536;
  gemm_core128(tm, W, bias, C, 512, 512, 0, bn*128, As, Bs);
}

// ---------------- MFMA flash attention (swapped QK^T, 32x32x16) ----------------
template<int NKEYS, int WRITE_ATTN, int KPF>
__global__ __launch_bounds__(256) void attn_mfma(
  const ushort* __restrict__ Qb, int qstr,
  const ushort* __restrict__ Kb, int kstr,
  const ushort* __restrict__ Vb, int vstr,
  ushort* __restrict__ Ob,
  float* __restrict__ attn_out)
{
  constexpr int NK2 = NKEYS*2;
  __shared__ __align__(16) ushort KsV[NKEYS*64 + 64*NKEYS];
  const int f = blockIdx.x, h = blockIdx.y;
  const int tid = threadIdx.x, lane = tid & 63, w = tid >> 6;
  const int l31 = lane & 31, l5 = lane >> 5;
  const int swz = (lane & 7) << 4;

  ushort* Ks = KsV;
  ushort* Vt = KsV + NKEYS*64;
  float* psum = (float*)Vt;   // aliased; pass 2 only, after barrier
  const ushort* kp0 = Kb + (size_t)(KPF ? f*256 : 0)*kstr + h*64;
  const ushort* vp0 = Vb + (size_t)(KPF ? f*256 : 0)*vstr + h*64;

  for (int c = tid; c < NKEYS*8; c += 256){
    int m = c>>3, dc = c&7;
    short8 k8 = *(const short8*)(kp0 + (size_t)m*kstr + dc*8);
    short8 v8 = *(const short8*)(vp0 + (size_t)m*vstr + dc*8);
    *(short8*)((char*)Ks + m*128 + ((dc*16) ^ ((m&7)<<4))) = k8;
    #pragma unroll
    for (int j=0;j<8;j++){
      int d = dc*8 + j;
      *(ushort*)((char*)Vt + d*NK2 + ((m*2) ^ (j<<4))) = (ushort)v8[j];
    }
  }

  short8 qb[2][4];
  const int q0 = w*64;
  const ushort* qp0 = Qb + (size_t)(f*256)*qstr + h*64;
  #pragma unroll
  for (int qj=0;qj<2;qj++)
    #pragma unroll
    for (int dc=0;dc<4;dc++)
      qb[qj][dc] = *(const short8*)(qp0 + (size_t)(q0 + qj*32 + l31)*qstr + dc*16 + l5*8);
  __syncthreads();

  f32x16 O[2][2];
  O[0][0]=zero16(); O[0][1]=zero16(); O[1][0]=zero16(); O[1][1]=zero16();
  float lpart[2] = {0.f, 0.f};

  for (int t = 0; t < NKEYS/32; t++){
    const int k0 = t*32;
    short8 ka[4];
    #pragma unroll
    for (int dc=0;dc<4;dc++)
      ka[dc] = *(const short8*)((char*)Ks + (k0+l31)*128 + (((dc*32) + (l5*16)) ^ swz));
    f32x16 s0 = zero16(), s1 = zero16();
    #pragma unroll
    for (int dc=0;dc<4;dc++){
      s0 = __builtin_amdgcn_mfma_f32_32x32x16_bf16(ka[dc], qb[0][dc], s0, 0,0,0);
      s1 = __builtin_amdgcn_mfma_f32_32x32x16_bf16(ka[dc], qb[1][dc], s1, 0,0,0);
    }
    uint pw[2][8];
    #pragma unroll
    for (int qj=0;qj<2;qj++){
      const f32x16& sv = qj ? s1 : s0;
      float p[16]; float lp = 0.f;
      #pragma unroll
      for (int r=0;r<16;r++){ p[r] = __expf(sv[r]*SCALEf); lp += p[r]; }
      lpart[qj] += lp;
      #pragma unroll
      for (int k=0;k<8;k++){
        uint w_;
        asm("v_cvt_pk_bf16_f32 %0, %1, %2" : "=v"(w_) : "v"(p[2*k]), "v"(p[2*k+1]));
        pw[qj][k] = w_;
      }
    }
    short8 pa[2][2];
    #pragma unroll
    for (int qj=0;qj<2;qj++){
      #pragma unroll
      for (int mj=0;mj<2;mj++){
        uint a0 = pw[qj][mj*4+2], b0 = pw[qj][mj*4+0];
        uint a1 = pw[qj][mj*4+3], b1 = pw[qj][mj*4+1];
        asm("v_permlane32_swap_b32 %0, %1" : "+v"(a0), "+v"(b0));
        asm("v_permlane32_swap_b32 %0, %1" : "+v"(a1), "+v"(b1));
        union { uint u[4]; short8 s8; } u_;
        u_.u[0]=b0; u_.u[1]=b1; u_.u[2]=a0; u_.u[3]=a1;
        pa[qj][mj] = u_.s8;
      }
    }
    #pragma unroll
    for (int mj=0;mj<2;mj++){
      short8 vbf[2];
      #pragma unroll
      for (int dj=0;dj<2;dj++)
        vbf[dj] = *(const short8*)((char*)Vt + (dj*32+l31)*NK2 + (((k0 + mj*16 + l5*8)*2) ^ swz));
      #pragma unroll
      for (int qj=0;qj<2;qj++)
        #pragma unroll
        for (int dj=0;dj<2;dj++)
          O[qj][dj] = __builtin_amdgcn_mfma_f32_32x32x16_bf16(pa[qj][mj], vbf[dj], O[qj][dj], 0,0,0);
    }
  }

  float invl[2];
  #pragma unroll
  for (int qj=0;qj<2;qj++){
    float lt = lpart[qj] + __shfl_xor(lpart[qj], 32, 64);
    invl[qj] = 1.f / lt;
  }

  ushort* op0 = Ob + (size_t)(f*256)*512 + h*64;
  #pragma unroll
  for (int qj=0;qj<2;qj++){
    #pragma unroll
    for (int r=0;r<16;r++){
      int qr = (r&3) + 8*(r>>2) + 4*l5;
      float il = __shfl(invl[qj], (lane & 32) | qr, 64);
      #pragma unroll
      for (int dj=0;dj<2;dj++){
        float v = O[qj][dj][r] * il;
        op0[(size_t)(q0 + qj*32 + qr)*512 + dj*32 + l31] = f2b(v);
      }
    }
  }

  if (WRITE_ATTN){
    __syncthreads();   // all waves done with Vt before psum aliases it
    for (int t = 0; t < NKEYS/32; t++){
      const int k0 = t*32;
      short8 ka[4];
      #pragma unroll
      for (int dc=0;dc<4;dc++)
        ka[dc] = *(const short8*)((char*)Ks + (k0+l31)*128 + (((dc*32) + (l5*16)) ^ swz));
      f32x16 s0 = zero16(), s1 = zero16();
      #pragma unroll
      for (int dc=0;dc<4;dc++){
        s0 = __builtin_amdgcn_mfma_f32_32x32x16_bf16(ka[dc], qb[0][dc], s0, 0,0,0);
        s1 = __builtin_amdgcn_mfma_f32_32x32x16_bf16(ka[dc], qb[1][dc], s1, 0,0,0);
      }
      float tsum[16];
      #pragma unroll
      for (int r=0;r<16;r++){
        float v = __expf(s0[r]*SCALEf)*invl[0] + __expf(s1[r]*SCALEf)*invl[1];
        #pragma unroll
        for (int mk=1; mk<=16; mk<<=1) v += __shfl_xor(v, mk, 64);
        tsum[r] = v;
      }
      if (l31 == 0){
        #pragma unroll
        for (int r=0;r<16;r++)
          psum[w*NKEYS + k0 + (r&3) + 8*(r>>2) + 4*l5] = tsum[r];
      }
    }
    __syncthreads();
    for (int m = tid; m < NKEYS; m += 256){
      attn_out[f*(Hh*NKEYS) + h*NKEYS + m] =
        (psum[0*NKEYS+m]+psum[1*NKEYS+m]+psum[2*NKEYS+m]+psum[3*NKEYS+m]) * (1.0f/256.0f);
    }
  }
}

// ---------------- Residual + LayerNorm (D=512), wave per row ----------------
__global__ __launch_bounds__(256) void ln_res(
  const ushort* __restrict__ X, const ushort* __restrict__ Oin,
  const float* __restrict__ g, const float* __restrict__ b,
  ushort* __restrict__ Y)
{
  const int row = blockIdx.x*4 + (threadIdx.x>>6);
  const int lane = threadIdx.x & 63;
  const ushort* xp = X + (size_t)row*512 + lane*8;
  const ushort* op = Oin + (size_t)row*512 + lane*8;
  uint xw[4], ow[4];
  *(int4_*)xw = *(const int4_*)xp;
  *(int4_*)ow = *(const int4_*)op;
  float v[8];
  #pragma unroll
  for(int j=0;j<4;j++){
    float xl,xh,ol,oh; unpack2(xw[j],xl,xh); unpack2(ow[j],ol,oh);
    v[2*j] = xl+ol; v[2*j+1] = xh+oh;
  }
  float s=0.f, sq=0.f;
  #pragma unroll
  for(int j=0;j<8;j++){ s += v[j]; sq += v[j]*v[j]; }
  s = wred(s); sq = wred(sq);
  float mu = s * (1.0f/512.0f);
  float var = sq * (1.0f/512.0f) - mu*mu;
  float rs = rsqrtf(var + EPSf);
  ushort ob[8];
  #pragma unroll
  for(int j=0;j<8;j++){
    ob[j] = f2b((v[j]-mu)*rs*g[lane*8+j] + b[lane*8+j]);
  }
  *(int4_*)(Y + (size_t)row*512 + lane*8) = *(const int4_*)ob;
}

// ---------------- Final LN (FD=256) -> fp32 d_out ----------------
__global__ __launch_bounds__(256) void ln_out(
  const ushort* __restrict__ A, const float* __restrict__ g,
  const float* __restrict__ b, float* __restrict__ out)
{
  const int row = blockIdx.x*4 + (threadIdx.x>>6);
  const int lane = threadIdx.x & 63;
  uint aw[2];
  *(int2_*)aw = *(const int2_*)(A + (size_t)row*256 + lane*4);
  float v[4];
  unpack2(aw[0], v[0], v[1]); unpack2(aw[1], v[2], v[3]);
  float s=0.f, sq=0.f;
  #pragma unroll
  for(int j=0;j<4;j++){ s += v[j]; sq += v[j]*v[j]; }
  s = wred(s); sq = wred(sq);
  float mu = s * (1.0f/256.0f);
  float var = sq * (1.0f/256.0f) - mu*mu;
  float rs = rsqrtf(var + EPSf);
  float4_ o;
  #pragma unroll
  for(int j=0;j<4;j++){
    o[j] = (v[j]-mu)*rs*g[lane*4+j] + b[lane*4+j];
  }
  *(float4_*)(out + (size_t)row*256 + lane*4) = o;
}

extern "C" void kernel_launch(void* const* d_in, const int* in_sizes, int n_in,
                              void* d_out, int out_size, void* d_ws, size_t ws_size,
                              hipStream_t stream) {
  const float* cur      = (const float*)d_in[0];
  const float* traj     = (const float*)d_in[1];
  const float* sa_in_w  = (const float*)d_in[2];
  const float* sa_in_b  = (const float*)d_in[3];
  const float* sa_out_w = (const float*)d_in[4];
  const float* sa_out_b = (const float*)d_in[5];
  const float* n1_g     = (const float*)d_in[6];
  const float* n1_b     = (const float*)d_in[7];
  const float* ca_qw    = (const float*)d_in[8];
  const float* ca_qb    = (const float*)d_in[9];
  const float* ca_kw    = (const float*)d_in[10];
  const float* ca_kb    = (const float*)d_in[11];
  const float* ca_vw    = (const float*)d_in[12];
  const float* ca_vb    = (const float*)d_in[13];
  const float* ca_ow    = (const float*)d_in[14];
  const float* ca_ob    = (const float*)d_in[15];
  const float* n2_g     = (const float*)d_in[16];
  const float* n2_b     = (const float*)d_in[17];
  const float* f_w1     = (const float*)d_in[18];
  const float* f_b1     = (const float*)d_in[19];
  const float* f_w2     = (const float*)d_in[20];
  const float* f_b2     = (const float*)d_in[21];
  const float* n3_g     = (const float*)d_in[22];
  const float* n3_b     = (const float*)d_in[23];
  const float* out_w    = (const float*)d_in[24];
  const float* out_b    = (const float*)d_in[25];
  const float* on_g     = (const float*)d_in[26];
  const float* on_b     = (const float*)d_in[27];

  float* out      = (float*)d_out;
  float* attn_out = out + (size_t)4*16*256*256;

  uint8_t* ws = (uint8_t*)d_ws;
  size_t off = 0;
  auto alloc = [&](size_t bytes)->uint8_t*{ uint8_t* p = ws + off; off += (bytes + 255) & ~(size_t)255; return p; };
  ushort* X   = (ushort*)alloc(16777216);
  ushort* B1  = (ushort*)alloc(50331648);
  ushort* B2  = (ushort*)alloc(16777216);
  ushort* KVm = (ushort*)alloc((size_t)6*2*65536*2);
  ushort* tm  = (ushort*)alloc(131072);
  ushort* w_sa_in  = (ushort*)alloc((size_t)5*1536*512*2);
  ushort* w_sa_out = (ushort*)alloc((size_t)5*512*512*2);
  ushort* w_ca_q   = (ushort*)alloc((size_t)6*512*512*2);
  ushort* w_ca_k   = (ushort*)alloc((size_t)6*512*512*2);
  ushort* w_ca_v   = (ushort*)alloc((size_t)6*512*512*2);
  ushort* w_ca_o   = (ushort*)alloc((size_t)6*512*512*2);
  ushort* w_f1     = (ushort*)alloc((size_t)6*1024*512*2);
  ushort* w_f2     = (ushort*)alloc((size_t)6*512*1024*2);
  ushort* w_out    = (ushort*)alloc((size_t)256*512*2);

  // one fused conversion + tmean dispatch (8 elems/thread)
  CvtTab tab;
  const float* srcs[10] = {cur, sa_in_w, sa_out_w, ca_qw, ca_kw, ca_vw, ca_ow, f_w1, f_w2, out_w};
  ushort* dsts[10]      = {X,   w_sa_in, w_sa_out, w_ca_q, w_ca_k, w_ca_v, w_ca_o, w_f1, w_f2, w_out};
  unsigned lens[10] = {16384u*512u, 5u*1536u*512u, 5u*512u*512u, 6u*512u*512u, 6u*512u*512u,
                       6u*512u*512u, 6u*512u*512u, 6u*1024u*512u, 6u*512u*1024u, 256u*512u};
  unsigned acc8 = 0;
  for (int i=0;i<10;i++){ tab.s[i]=srcs[i]; tab.d[i]=dsts[i]; tab.st[i]=acc8; acc8 += lens[i]/8; }
  tab.st[10] = acc8;
  unsigned nbcvt = (acc8 + 255)/256;
  cvt_tm<<<nbcvt + 256, 256, 0, stream>>>(tab, nbcvt, traj, tm);
  kv_all<<<48,256,0,stream>>>(tm, w_ca_k, w_ca_v, ca_kb, ca_vb, KVm);

  for (int i=0;i<NLl;i++){
    if (i>=1){
      int j = i-1;
      gemm_bias<0><<<12*128,512,0,stream>>>(X, w_sa_in + (size_t)j*1536*512, sa_in_b + j*1536, B1, 1536, 512, 12);
      attn_mfma<256,0,1><<<dim3(64,8),256,0,stream>>>(B1, 1536, B1+512, 1536, B1+1024, 1536, B2, nullptr);
      gemm_bias<0><<<4*128,512,0,stream>>>(B2, w_sa_out + (size_t)j*262144, sa_out_b + j*512, B1, 512, 512, 4);
      ln_res<<<4096,256,0,stream>>>(X, B1, n1_g + j*512, n1_b + j*512, X);
    }
    gemm_bias<0><<<4*128,512,0,stream>>>(X, w_ca_q + (size_t)i*262144, ca_qb + i*512, B2, 512, 512, 4);
    attn_mfma<128,1,0><<<dim3(64,8),256,0,stream>>>(B2, 512, KVm + (size_t)i*131072, 512, KVm + (size_t)i*131072 + 65536, 512, B1, attn_out + (size_t)i*65536);
    gemm_bias<0><<<4*128,512,0,stream>>>(B1, w_ca_o + (size_t)i*262144, ca_ob + i*512, B2, 512, 512, 4);
    ln_res<<<4096,256,0,stream>>>(X, B2, n2_g + i*512, n2_b + i*512, X);
    gemm_bias<1><<<8*128,512,0,stream>>>(X, w_f1 + (size_t)i*524288, f_b1 + i*1024, B1, 1024, 512, 8);
    gemm_bias<0><<<4*128,512,0,stream>>>(B1, w_f2 + (size_t)i*524288, f_b2 + i*512, B2, 512, 1024, 4);
    ln_res<<<4096,256,0,stream>>>(X, B2, n3_g + i*512, n3_b + i*512, X);
  }
  gemm_bias<0><<<2*128,512,0,stream>>>(X, w_out, out_b, B2, 256, 512, 2);
  ln_out<<<4096,256,0,stream>>>(B2, on_g, on_b, out);
}